// Round 27
// baseline (63.548 us; speedup 1.0000x reference)
//
#include <hip/hip_runtime.h>
#include <hip/hip_bf16.h>
#include <stdint.h>

#define I_DIM 2048
#define O_DIM 8192
#define T_TOK 512
#define NSTR  64
#define BK    64
#define NSTEP (I_DIM / BK)

#define TILE_B 16384  // bytes per (stripe,step): B-hi, FRAGMENT-MAJOR layout

// gemm22 LDS: A-hi dbuf 2 x 8KB = 16KB, thr 8KB @ 16384 -> 24KB
#define THR_S 16384
#define SMEM22 24576

// workspace layout (PM grown to 4MB: 128 x 8192 f32 partials)
#define WT_OFF   ((size_t)0)             // 32MB weight hi-tiles (fragment-major)
#define XC_OFF   ((size_t)67108864)      // 4MB xc f32
#define THR_OFF  ((size_t)71303168)      // 512KB thrs f32[64][2048]
#define PM_OFF   ((size_t)71827456)      // 4MB pm_part f32[128][8192]
#define PMB_OFF  ((size_t)76021760)      // 32KB pmb f32[8192]
#define CNT_OFF  ((size_t)76054528)      // 2KB counts i32[512]

typedef __attribute__((ext_vector_type(8))) short bf16x8;
typedef __attribute__((ext_vector_type(4))) float f32x4;
typedef __attribute__((ext_vector_type(4))) int i32x4;

// k0: MERGED prep + wprep3. Blocks 0..2047: 16-row x 512-col weight prep
// (32KB LDS -> 4+ blocks/CU for latency hiding; fragment writes disjoint).
// Blocks 2048..3071: xc/thrs/counts prep (concurrent).
__global__ __launch_bounds__(256) void cwic_prep_all(
    const float* __restrict__ w, const float* __restrict__ mu,
    const float* __restrict__ x, const float* __restrict__ thresholds,
    const float* __restrict__ stdv, char* __restrict__ wt,
    float* __restrict__ pm_part, float* __restrict__ xc,
    float* __restrict__ thrs, int* __restrict__ counts) {
  const int tid = threadIdx.x;
  __shared__ float ls[16][512];  // 32KB (unused by prep branch)

  if (blockIdx.x >= 2048) {
    // ---- prep branch: xc = x - mu; thrs = thresholds*std; zero counts ----
    int idx = (blockIdx.x - 2048) * 256 + tid;  // 262144 float4s of xc
    float4 xv = ((const float4*)x)[idx];
    float4 mv = ((const float4*)mu)[idx & 511];
    float4 r;
    r.x = xv.x - mv.x; r.y = xv.y - mv.y; r.z = xv.z - mv.z; r.w = xv.w - mv.w;
    ((float4*)xc)[idx] = r;
    if (idx < (NSTR * I_DIM) / 4) {
      float4 t = ((const float4*)thresholds)[idx];
      float4 s = ((const float4*)stdv)[idx & 511];
      float4 ts;
      ts.x = t.x * s.x; ts.y = t.y * s.y; ts.z = t.z * s.z; ts.w = t.w * s.w;
      ((float4*)thrs)[idx] = ts;
    }
    if (idx < T_TOK) counts[idx] = 0;
    return;
  }

  // ---- wprep3 branch: quarter-step = 16 w-rows ----
  const int bp = blockIdx.x;       // 2048 = 128 quarter-steps x 16 col-chunks
  const int qs = bp >> 4, cc = bp & 15;
  const int step = qs >> 2, kh = (qs >> 1) & 1, gh = qs & 1;  // g-pair gh*2+{0,1}
  const int r0 = qs * 16;
  {
    const int sr = tid >> 7, sf = tid & 127;
    #pragma unroll 4
    for (int p = 0; p < 8; ++p) {
      const int row = p * 2 + sr;
      float4 v = *(const float4*)(w + (size_t)(r0 + row) * O_DIM + cc * 512 + sf * 4);
      *(float4*)&ls[row][sf * 4] = v;
    }
  }
  __syncthreads();

  float mus[16];
  #pragma unroll
  for (int r = 0; r < 16; ++r) mus[r] = mu[r0 + r];

  #pragma unroll
  for (int ci = 0; ci < 2; ++ci) {
    const int c = tid + ci * 256;
    const int C = cc * 512 + c;
    const int n = C >> 7, o = C & 127;
    char* tb = wt + (size_t)(n * NSTEP + step) * TILE_B + (kh * 8 + (o >> 4)) * 1024;
    float pm = 0.0f;
    #pragma unroll
    for (int gg = 0; gg < 2; ++gg) {
      const int g = gh * 2 + gg;
      unsigned hv[4];
      unsigned hprev = 0;
      #pragma unroll
      for (int e = 0; e < 8; ++e) {
        float v = ls[gg * 8 + e][c];
        pm += mus[gg * 8 + e] * v;
        unsigned u = __builtin_bit_cast(unsigned, v);
        unsigned r = u + 0x7fffu + ((u >> 16) & 1u);   // RNE to bf16
        unsigned short h = (unsigned short)(r >> 16);
        if ((e & 1) == 0) hprev = h;
        else hv[e >> 1] = hprev | (((unsigned)h) << 16);
      }
      *(i32x4*)(tb + ((o & 15) + g * 16) * 16) = *(i32x4*)hv;
    }
    pm_part[(size_t)qs * O_DIM + C] = pm;
  }
}

// k1: pmb[o] = bias[o] + sum_{j=0..127} pm_part[j][o] (fixed order, deterministic)
__global__ void cwic_pmb(const float* __restrict__ pm_part,
                         const float* __restrict__ bias, float* __restrict__ pmb) {
  int o = blockIdx.x * 256 + threadIdx.x;
  float s = bias[o];
  #pragma unroll 8
  for (int j = 0; j < 128; ++j) s += pm_part[(size_t)j * O_DIM + o];
  pmb[o] = s;
}

// k2: masked GEMM "B-direct, 1-product, 8-wave, A-build-ahead" (R26-verified).
__global__ __launch_bounds__(512, 4) void cwic_gemm22(
    const float* __restrict__ xc, const char* __restrict__ wt,
    const float* __restrict__ thrs, const float* __restrict__ pmb,
    float* __restrict__ y, int* __restrict__ counts) {
  extern __shared__ char smem[];
  const int b = blockIdx.x;
  // XCD swizzle: the 8 token-tiles of one stripe share an XCD -> tiles L2-hot.
  const int nid = (b & 7) * 64 + (b >> 3);
  const int n = nid >> 3, tt = nid & 7;
  const int trow0 = tt * 64, ocol0 = n * 128;
  const int tid = threadIdx.x;
  const int lane = tid & 63, wid = tid >> 6;      // 8 waves
  const int wr = wid >> 2, wc = wid & 3;          // 2 x 4
  const int l15 = lane & 15, l4 = lane >> 4;
  const int t_loc = tid >> 3, kq = tid & 7;       // A staging: row (0..63), k-octet

  float* thr_s = (float*)(smem + THR_S);
  ((float4*)thr_s)[tid] = ((const float4*)(thrs + (size_t)n * I_DIM))[tid];

  const float* xrow = xc + (size_t)(trow0 + t_loc) * I_DIM + kq * 8;
  const char* wfrag = wt + (size_t)(n * NSTEP) * TILE_B + (wc * 2) * 1024 + lane * 16;

  f32x4 acc[2][2];
  #pragma unroll
  for (int mi = 0; mi < 2; ++mi)
    #pragma unroll
    for (int ni = 0; ni < 2; ++ni) acc[mi][ni] = (f32x4)(0.0f);
  int cnt = 0;

  bf16x8 bA0, bA1, bA2, bA3, bB0, bB1, bB2, bB3;
  bA0 = *(const bf16x8*)(wfrag + 0 * 1024);
  bA1 = *(const bf16x8*)(wfrag + 1 * 1024);
  bA2 = *(const bf16x8*)(wfrag + 8 * 1024);
  bA3 = *(const bf16x8*)(wfrag + 9 * 1024);
  float4 xp0 = *(const float4*)(xrow);
  float4 xp1 = *(const float4*)(xrow + 4);
  __syncthreads();  // thr_s ready

  // A-build(0) -> buf0
  {
    float4 tv0 = *(const float4*)(thr_s + kq * 8);
    float4 tv1 = *(const float4*)(thr_s + kq * 8 + 4);
    const float xs[8] = {xp0.x, xp0.y, xp0.z, xp0.w, xp1.x, xp1.y, xp1.z, xp1.w};
    const float ts[8] = {tv0.x, tv0.y, tv0.z, tv0.w, tv1.x, tv1.y, tv1.z, tv1.w};
    bf16x8 hv8;
    #pragma unroll
    for (int e = 0; e < 8; ++e) {
      bool keep = fabsf(xs[e]) > ts[e];
      cnt += keep ? 1 : 0;
      float a = keep ? xs[e] : 0.0f;
      __hip_bfloat16 h = __float2bfloat16(a);
      hv8[e] = __builtin_bit_cast(short, h);
    }
    const int ad = t_loc * 128 + ((kq * 16) ^ ((t_loc & 7) << 4));
    *(bf16x8*)(smem + 0 + ad) = hv8;
  }
  __syncthreads();  // A(0) visible

#define STEP22(STEP_I, CUR, B0, B1, B2, B3, NB0, NB1, NB2, NB3)                \
  {                                                                            \
    const int step_ = (STEP_I);                                                \
    const int s1_ = step_ + 1;                                                 \
    const int sc_ = (s1_ < NSTEP) ? s1_ : step_;                               \
    {                                                                          \
      const char* bp_ = wfrag + (size_t)sc_ * TILE_B;                          \
      NB0 = *(const bf16x8*)(bp_ + 0 * 1024);                                  \
      NB1 = *(const bf16x8*)(bp_ + 1 * 1024);                                  \
      NB2 = *(const bf16x8*)(bp_ + 8 * 1024);                                  \
      NB3 = *(const bf16x8*)(bp_ + 9 * 1024);                                  \
    }                                                                          \
    float4 xn0 = *(const float4*)(xrow + sc_ * BK);                            \
    float4 xn1 = *(const float4*)(xrow + sc_ * BK + 4);                        \
    __builtin_amdgcn_s_setprio(1);                                             \
    _Pragma("unroll") for (int s32 = 0; s32 < 2; ++s32) {                      \
      bf16x8 afh[2];                                                           \
      _Pragma("unroll") for (int mi = 0; mi < 2; ++mi) {                       \
        const int r = wr * 32 + mi * 16 + l15;                                 \
        const int ada = r * 128 + (((s32 * 64) + l4 * 16) ^ ((r & 7) << 4));   \
        afh[mi] = *(const bf16x8*)(smem + (CUR) + ada);                        \
      }                                                                        \
      bf16x8 bh0 = (s32 == 0) ? B0 : B2;                                       \
      bf16x8 bh1 = (s32 == 0) ? B1 : B3;                                       \
      _Pragma("unroll") for (int mi = 0; mi < 2; ++mi) {                       \
        acc[mi][0] = __builtin_amdgcn_mfma_f32_16x16x32_bf16(afh[mi], bh0, acc[mi][0], 0, 0, 0); \
        acc[mi][1] = __builtin_amdgcn_mfma_f32_16x16x32_bf16(afh[mi], bh1, acc[mi][1], 0, 0, 0); \
      }                                                                        \
    }                                                                          \
    __builtin_amdgcn_s_setprio(0);                                             \
    if (s1_ < NSTEP) {                                                         \
      float4 tv0 = *(const float4*)(thr_s + s1_ * BK + kq * 8);                \
      float4 tv1 = *(const float4*)(thr_s + s1_ * BK + kq * 8 + 4);            \
      const float xs[8] = {xn0.x, xn0.y, xn0.z, xn0.w, xn1.x, xn1.y, xn1.z, xn1.w}; \
      const float ts[8] = {tv0.x, tv0.y, tv0.z, tv0.w, tv1.x, tv1.y, tv1.z, tv1.w}; \
      bf16x8 hv8;                                                              \
      _Pragma("unroll") for (int e = 0; e < 8; ++e) {                          \
        bool keep = fabsf(xs[e]) > ts[e];                                      \
        cnt += keep ? 1 : 0;                                                   \
        float a = keep ? xs[e] : 0.0f;                                         \
        __hip_bfloat16 h = __float2bfloat16(a);                                \
        hv8[e] = __builtin_bit_cast(short, h);                                 \
      }                                                                        \
      const int ad = t_loc * 128 + ((kq * 16) ^ ((t_loc & 7) << 4));           \
      *(bf16x8*)(smem + ((CUR) ^ 8192) + ad) = hv8;                            \
    }                                                                          \
    __syncthreads();                                                           \
  }

  for (int sp = 0; sp < NSTEP; sp += 2) {
    STEP22(sp,     0,    bA0, bA1, bA2, bA3, bB0, bB1, bB2, bB3);
    STEP22(sp + 1, 8192, bB0, bB1, bB2, bB3, bA0, bA1, bA2, bA3);
  }
#undef STEP22

  // ---- mask-count reduce: 8 threads (kq) share one token row ----
  cnt += __shfl_xor(cnt, 1);
  cnt += __shfl_xor(cnt, 2);
  cnt += __shfl_xor(cnt, 4);
  if (kq == 0) atomicAdd(&counts[trow0 + t_loc], cnt);

  // ---- epilogue: y = acc + (post_mu + bias); C/D layout m89-verified ----
  #pragma unroll
  for (int ni = 0; ni < 2; ++ni) {
    const int o = ocol0 + wc * 32 + ni * 16 + l15;
    const float pv = pmb[o];
    #pragma unroll
    for (int mi = 0; mi < 2; ++mi) {
      const int row0 = trow0 + wr * 32 + mi * 16 + l4 * 4;
      #pragma unroll
      for (int r = 0; r < 4; ++r) {
        y[(size_t)(row0 + r) * O_DIM + o] = acc[mi][ni][r] + pv;
      }
    }
  }
}

// k3: flops outputs. flops_sparse = 16777216 * cnt/(64*2048) = 128*cnt (exact).
__global__ void cwic_fin(const int* __restrict__ counts, float* __restrict__ outF) {
  int t = blockIdx.x * 256 + threadIdx.x;
  outF[t] = 16777216.0f;
  outF[T_TOK + t] = 128.0f * (float)counts[t];
}

extern "C" void kernel_launch(void* const* d_in, const int* in_sizes, int n_in,
                              void* d_out, int out_size, void* d_ws, size_t ws_size,
                              hipStream_t stream) {
  const float* x = (const float*)d_in[0];
  const float* w = (const float*)d_in[1];
  const float* bias = (const float*)d_in[2];
  const float* thresholds = (const float*)d_in[3];
  const float* mu = (const float*)d_in[4];
  const float* stdv = (const float*)d_in[5];
  float* y = (float*)d_out;

  char* ws = (char*)d_ws;
  char* wt = ws + WT_OFF;
  float* xc = (float*)(ws + XC_OFF);
  float* thrs = (float*)(ws + THR_OFF);
  float* pm_part = (float*)(ws + PM_OFF);
  float* pmb = (float*)(ws + PMB_OFF);
  int* counts = (int*)(ws + CNT_OFF);

  cwic_prep_all<<<3072, 256, 0, stream>>>(w, mu, x, thresholds, stdv, wt,
                                          pm_part, xc, thrs, counts);
  cwic_pmb<<<32, 256, 0, stream>>>(pm_part, bias, pmb);
  cwic_gemm22<<<512, 512, SMEM22, stream>>>(xc, wt, thrs, pmb, y, counts);
  cwic_fin<<<2, 256, 0, stream>>>(counts, y + (size_t)T_TOK * O_DIM);
}

// Round 28
// 62.778 us; speedup vs baseline: 1.0123x; 1.0123x over previous
//
#include <hip/hip_runtime.h>
#include <hip/hip_bf16.h>
#include <stdint.h>

#define I_DIM 2048
#define O_DIM 8192
#define T_TOK 512
#define NSTR  64
#define BK    64
#define NSTEP (I_DIM / BK)

#define TILE_B 16384  // bytes per (stripe,step): B-hi, FRAGMENT-MAJOR layout

// gemm22 LDS: A-hi dbuf 2 x 8KB = 16KB, thr 8KB @ 16384 -> 24KB
#define THR_S 16384
#define SMEM22 24576

// workspace layout
#define WT_OFF   ((size_t)0)             // 32MB weight hi-tiles (fragment-major)
#define XC_OFF   ((size_t)67108864)      // 4MB xc f32
#define THR_OFF  ((size_t)71303168)      // 512KB thrs f32[64][2048]
#define PM_OFF   ((size_t)71827456)      // 2MB pm_part f32[64][8192]
#define PMB_OFF  ((size_t)73924608)      // 32KB pmb f32[8192]
#define CNT_OFF  ((size_t)73957376)      // 2KB counts i32[512]

typedef __attribute__((ext_vector_type(8))) short bf16x8;
typedef __attribute__((ext_vector_type(4))) float f32x4;
typedef __attribute__((ext_vector_type(4))) int i32x4;

// k0: MERGED prep + wprep2 (R25/R26-verified 64KB version; R27's 32KB variant
// regressed — reverted).
__global__ __launch_bounds__(256) void cwic_prep_all(
    const float* __restrict__ w, const float* __restrict__ mu,
    const float* __restrict__ x, const float* __restrict__ thresholds,
    const float* __restrict__ stdv, char* __restrict__ wt,
    float* __restrict__ pm_part, float* __restrict__ xc,
    float* __restrict__ thrs, int* __restrict__ counts) {
  const int tid = threadIdx.x;
  __shared__ float ls[32][512];  // 64KB (unused by prep branch)

  if (blockIdx.x >= 1024) {
    int idx = (blockIdx.x - 1024) * 256 + tid;  // 262144 float4s of xc
    float4 xv = ((const float4*)x)[idx];
    float4 mv = ((const float4*)mu)[idx & 511];
    float4 r;
    r.x = xv.x - mv.x; r.y = xv.y - mv.y; r.z = xv.z - mv.z; r.w = xv.w - mv.w;
    ((float4*)xc)[idx] = r;
    if (idx < (NSTR * I_DIM) / 4) {
      float4 t = ((const float4*)thresholds)[idx];
      float4 s = ((const float4*)stdv)[idx & 511];
      float4 ts;
      ts.x = t.x * s.x; ts.y = t.y * s.y; ts.z = t.z * s.z; ts.w = t.w * s.w;
      ((float4*)thrs)[idx] = ts;
    }
    if (idx < T_TOK) counts[idx] = 0;
    return;
  }

  const int bp = blockIdx.x;       // 1024 = 64 half-steps x 16 col-chunks
  const int hs = bp >> 4, cc = bp & 15;
  const int step = hs >> 1, kh = hs & 1;
  const int r0 = hs * 32;
  {
    const int sr = tid >> 7, sf = tid & 127;
    #pragma unroll 4
    for (int p = 0; p < 16; ++p) {
      const int row = p * 2 + sr;
      float4 v = *(const float4*)(w + (size_t)(r0 + row) * O_DIM + cc * 512 + sf * 4);
      *(float4*)&ls[row][sf * 4] = v;
    }
  }
  __syncthreads();

  float mus[32];
  #pragma unroll
  for (int r = 0; r < 32; ++r) mus[r] = mu[r0 + r];

  #pragma unroll
  for (int ci = 0; ci < 2; ++ci) {
    const int c = tid + ci * 256;
    const int C = cc * 512 + c;
    const int n = C >> 7, o = C & 127;
    char* tb = wt + (size_t)(n * NSTEP + step) * TILE_B + (kh * 8 + (o >> 4)) * 1024;
    float pm = 0.0f;
    #pragma unroll
    for (int g = 0; g < 4; ++g) {
      unsigned hv[4];
      unsigned hprev = 0;
      #pragma unroll
      for (int e = 0; e < 8; ++e) {
        float v = ls[g * 8 + e][c];
        pm += mus[g * 8 + e] * v;
        unsigned u = __builtin_bit_cast(unsigned, v);
        unsigned r = u + 0x7fffu + ((u >> 16) & 1u);   // RNE to bf16
        unsigned short h = (unsigned short)(r >> 16);
        if ((e & 1) == 0) hprev = h;
        else hv[e >> 1] = hprev | (((unsigned)h) << 16);
      }
      *(i32x4*)(tb + ((o & 15) + g * 16) * 16) = *(i32x4*)hv;
    }
    pm_part[(size_t)(step * 2 + kh) * O_DIM + C] = pm;
  }
}

// k1: pmb[o] = bias[o] + sum_s pm_part[s][o] (fixed order, deterministic)
__global__ void cwic_pmb(const float* __restrict__ pm_part,
                         const float* __restrict__ bias, float* __restrict__ pmb) {
  int o = blockIdx.x * 256 + threadIdx.x;
  float s = bias[o];
  #pragma unroll 8
  for (int j = 0; j < 64; ++j) s += pm_part[(size_t)j * O_DIM + o];
  pmb[o] = s;
}

// k2: masked GEMM "B-direct, 1-product, 8-wave, A-build-ahead" (R26) with
// s_setprio REMOVED (A/B per m190: setprio hurts barrier-lockstep GEMM; only
// pays with wave role-diversity, which this lockstep schedule lacks).
__global__ __launch_bounds__(512, 4) void cwic_gemm22(
    const float* __restrict__ xc, const char* __restrict__ wt,
    const float* __restrict__ thrs, const float* __restrict__ pmb,
    float* __restrict__ y, int* __restrict__ counts) {
  extern __shared__ char smem[];
  const int b = blockIdx.x;
  // XCD swizzle: the 8 token-tiles of one stripe share an XCD -> tiles L2-hot.
  const int nid = (b & 7) * 64 + (b >> 3);
  const int n = nid >> 3, tt = nid & 7;
  const int trow0 = tt * 64, ocol0 = n * 128;
  const int tid = threadIdx.x;
  const int lane = tid & 63, wid = tid >> 6;      // 8 waves
  const int wr = wid >> 2, wc = wid & 3;          // 2 x 4
  const int l15 = lane & 15, l4 = lane >> 4;
  const int t_loc = tid >> 3, kq = tid & 7;       // A staging: row (0..63), k-octet

  float* thr_s = (float*)(smem + THR_S);
  ((float4*)thr_s)[tid] = ((const float4*)(thrs + (size_t)n * I_DIM))[tid];

  const float* xrow = xc + (size_t)(trow0 + t_loc) * I_DIM + kq * 8;
  const char* wfrag = wt + (size_t)(n * NSTEP) * TILE_B + (wc * 2) * 1024 + lane * 16;

  f32x4 acc[2][2];
  #pragma unroll
  for (int mi = 0; mi < 2; ++mi)
    #pragma unroll
    for (int ni = 0; ni < 2; ++ni) acc[mi][ni] = (f32x4)(0.0f);
  int cnt = 0;

  bf16x8 bA0, bA1, bA2, bA3, bB0, bB1, bB2, bB3;
  bA0 = *(const bf16x8*)(wfrag + 0 * 1024);
  bA1 = *(const bf16x8*)(wfrag + 1 * 1024);
  bA2 = *(const bf16x8*)(wfrag + 8 * 1024);
  bA3 = *(const bf16x8*)(wfrag + 9 * 1024);
  float4 xp0 = *(const float4*)(xrow);
  float4 xp1 = *(const float4*)(xrow + 4);
  __syncthreads();  // thr_s ready

  // A-build(0) -> buf0
  {
    float4 tv0 = *(const float4*)(thr_s + kq * 8);
    float4 tv1 = *(const float4*)(thr_s + kq * 8 + 4);
    const float xs[8] = {xp0.x, xp0.y, xp0.z, xp0.w, xp1.x, xp1.y, xp1.z, xp1.w};
    const float ts[8] = {tv0.x, tv0.y, tv0.z, tv0.w, tv1.x, tv1.y, tv1.z, tv1.w};
    bf16x8 hv8;
    #pragma unroll
    for (int e = 0; e < 8; ++e) {
      bool keep = fabsf(xs[e]) > ts[e];
      cnt += keep ? 1 : 0;
      float a = keep ? xs[e] : 0.0f;
      __hip_bfloat16 h = __float2bfloat16(a);
      hv8[e] = __builtin_bit_cast(short, h);
    }
    const int ad = t_loc * 128 + ((kq * 16) ^ ((t_loc & 7) << 4));
    *(bf16x8*)(smem + 0 + ad) = hv8;
  }
  __syncthreads();  // A(0) visible

#define STEP22(STEP_I, CUR, B0, B1, B2, B3, NB0, NB1, NB2, NB3)                \
  {                                                                            \
    const int step_ = (STEP_I);                                                \
    const int s1_ = step_ + 1;                                                 \
    const int sc_ = (s1_ < NSTEP) ? s1_ : step_;                               \
    /* (1) issue B(step+1) -> other static regs */                             \
    {                                                                          \
      const char* bp_ = wfrag + (size_t)sc_ * TILE_B;                          \
      NB0 = *(const bf16x8*)(bp_ + 0 * 1024);                                  \
      NB1 = *(const bf16x8*)(bp_ + 1 * 1024);                                  \
      NB2 = *(const bf16x8*)(bp_ + 8 * 1024);                                  \
      NB3 = *(const bf16x8*)(bp_ + 9 * 1024);                                  \
    }                                                                          \
    /* (2) issue x(step+1) (latency hides under MFMA) */                       \
    float4 xn0 = *(const float4*)(xrow + sc_ * BK);                            \
    float4 xn1 = *(const float4*)(xrow + sc_ * BK + 4);                        \
    /* (3) MFMA(step): A from LDS[CUR], B from regs (landed last step) */      \
    _Pragma("unroll") for (int s32 = 0; s32 < 2; ++s32) {                      \
      bf16x8 afh[2];                                                           \
      _Pragma("unroll") for (int mi = 0; mi < 2; ++mi) {                       \
        const int r = wr * 32 + mi * 16 + l15;                                 \
        const int ada = r * 128 + (((s32 * 64) + l4 * 16) ^ ((r & 7) << 4));   \
        afh[mi] = *(const bf16x8*)(smem + (CUR) + ada);                        \
      }                                                                        \
      bf16x8 bh0 = (s32 == 0) ? B0 : B2;                                       \
      bf16x8 bh1 = (s32 == 0) ? B1 : B3;                                       \
      _Pragma("unroll") for (int mi = 0; mi < 2; ++mi) {                       \
        acc[mi][0] = __builtin_amdgcn_mfma_f32_16x16x32_bf16(afh[mi], bh0, acc[mi][0], 0, 0, 0); \
        acc[mi][1] = __builtin_amdgcn_mfma_f32_16x16x32_bf16(afh[mi], bh1, acc[mi][1], 0, 0, 0); \
      }                                                                        \
    }                                                                          \
    /* (4) A-build(step+1) into LDS[CUR^1] (skipped on final step) */          \
    if (s1_ < NSTEP) {                                                         \
      float4 tv0 = *(const float4*)(thr_s + s1_ * BK + kq * 8);                \
      float4 tv1 = *(const float4*)(thr_s + s1_ * BK + kq * 8 + 4);            \
      const float xs[8] = {xn0.x, xn0.y, xn0.z, xn0.w, xn1.x, xn1.y, xn1.z, xn1.w}; \
      const float ts[8] = {tv0.x, tv0.y, tv0.z, tv0.w, tv1.x, tv1.y, tv1.z, tv1.w}; \
      bf16x8 hv8;                                                              \
      _Pragma("unroll") for (int e = 0; e < 8; ++e) {                          \
        bool keep = fabsf(xs[e]) > ts[e];                                      \
        cnt += keep ? 1 : 0;                                                   \
        float a = keep ? xs[e] : 0.0f;                                         \
        __hip_bfloat16 h = __float2bfloat16(a);                                \
        hv8[e] = __builtin_bit_cast(short, h);                                 \
      }                                                                        \
      const int ad = t_loc * 128 + ((kq * 16) ^ ((t_loc & 7) << 4));           \
      *(bf16x8*)(smem + ((CUR) ^ 8192) + ad) = hv8;                            \
    }                                                                          \
    __syncthreads(); /* publish A(step+1); separates buf reuse across iters */ \
  }

  for (int sp = 0; sp < NSTEP; sp += 2) {
    STEP22(sp,     0,    bA0, bA1, bA2, bA3, bB0, bB1, bB2, bB3);
    STEP22(sp + 1, 8192, bB0, bB1, bB2, bB3, bA0, bA1, bA2, bA3);
  }
#undef STEP22

  // ---- mask-count reduce: 8 threads (kq) share one token row ----
  cnt += __shfl_xor(cnt, 1);
  cnt += __shfl_xor(cnt, 2);
  cnt += __shfl_xor(cnt, 4);
  if (kq == 0) atomicAdd(&counts[trow0 + t_loc], cnt);

  // ---- epilogue: y = acc + (post_mu + bias); C/D layout m89-verified ----
  #pragma unroll
  for (int ni = 0; ni < 2; ++ni) {
    const int o = ocol0 + wc * 32 + ni * 16 + l15;
    const float pv = pmb[o];
    #pragma unroll
    for (int mi = 0; mi < 2; ++mi) {
      const int row0 = trow0 + wr * 32 + mi * 16 + l4 * 4;
      #pragma unroll
      for (int r = 0; r < 4; ++r) {
        y[(size_t)(row0 + r) * O_DIM + o] = acc[mi][ni][r] + pv;
      }
    }
  }
}

// k3: flops outputs. flops_sparse = 16777216 * cnt/(64*2048) = 128*cnt (exact).
__global__ void cwic_fin(const int* __restrict__ counts, float* __restrict__ outF) {
  int t = blockIdx.x * 256 + threadIdx.x;
  outF[t] = 16777216.0f;
  outF[T_TOK + t] = 128.0f * (float)counts[t];
}

extern "C" void kernel_launch(void* const* d_in, const int* in_sizes, int n_in,
                              void* d_out, int out_size, void* d_ws, size_t ws_size,
                              hipStream_t stream) {
  const float* x = (const float*)d_in[0];
  const float* w = (const float*)d_in[1];
  const float* bias = (const float*)d_in[2];
  const float* thresholds = (const float*)d_in[3];
  const float* mu = (const float*)d_in[4];
  const float* stdv = (const float*)d_in[5];
  float* y = (float*)d_out;

  char* ws = (char*)d_ws;
  char* wt = ws + WT_OFF;
  float* xc = (float*)(ws + XC_OFF);
  float* thrs = (float*)(ws + THR_OFF);
  float* pm_part = (float*)(ws + PM_OFF);
  float* pmb = (float*)(ws + PMB_OFF);
  int* counts = (int*)(ws + CNT_OFF);

  cwic_prep_all<<<2048, 256, 0, stream>>>(w, mu, x, thresholds, stdv, wt,
                                          pm_part, xc, thrs, counts);
  cwic_pmb<<<32, 256, 0, stream>>>(pm_part, bias, pmb);
  cwic_gemm22<<<512, 512, SMEM22, stream>>>(xc, wt, thrs, pmb, y, counts);
  cwic_fin<<<2, 256, 0, stream>>>(counts, y + (size_t)T_TOK * O_DIM);
}

// Round 29
// 61.413 us; speedup vs baseline: 1.0348x; 1.0222x over previous
//
#include <hip/hip_runtime.h>
#include <hip/hip_bf16.h>
#include <stdint.h>

#define I_DIM 2048
#define O_DIM 8192
#define T_TOK 512
#define NSTR  64
#define BK    64
#define NSTEP (I_DIM / BK)

#define TILE_B 16384  // bytes per (stripe,step): B-hi, FRAGMENT-MAJOR layout

// gemm22 LDS: A-hi dbuf 2 x 8KB = 16KB, thr 8KB @ 16384 -> 24KB
#define THR_S 16384
#define SMEM22 24576

// workspace layout
#define WT_OFF   ((size_t)0)             // 32MB weight hi-tiles (fragment-major)
#define XC_OFF   ((size_t)67108864)      // 4MB xc f32
#define THR_OFF  ((size_t)71303168)      // 512KB thrs f32[64][2048]
#define PM_OFF   ((size_t)71827456)      // 2MB pm_part f32[64][8192]
#define PMB_OFF  ((size_t)73924608)      // 32KB pmb f32[8192]
#define CNT_OFF  ((size_t)73957376)      // 2KB counts i32[512]

typedef __attribute__((ext_vector_type(8))) short bf16x8;
typedef __attribute__((ext_vector_type(4))) float f32x4;
typedef __attribute__((ext_vector_type(4))) int i32x4;

// k0: MERGED prep + wprep2 (R25/R26-verified 64KB version).
__global__ __launch_bounds__(256) void cwic_prep_all(
    const float* __restrict__ w, const float* __restrict__ mu,
    const float* __restrict__ x, const float* __restrict__ thresholds,
    const float* __restrict__ stdv, char* __restrict__ wt,
    float* __restrict__ pm_part, float* __restrict__ xc,
    float* __restrict__ thrs, int* __restrict__ counts) {
  const int tid = threadIdx.x;
  __shared__ float ls[32][512];  // 64KB (unused by prep branch)

  if (blockIdx.x >= 1024) {
    int idx = (blockIdx.x - 1024) * 256 + tid;  // 262144 float4s of xc
    float4 xv = ((const float4*)x)[idx];
    float4 mv = ((const float4*)mu)[idx & 511];
    float4 r;
    r.x = xv.x - mv.x; r.y = xv.y - mv.y; r.z = xv.z - mv.z; r.w = xv.w - mv.w;
    ((float4*)xc)[idx] = r;
    if (idx < (NSTR * I_DIM) / 4) {
      float4 t = ((const float4*)thresholds)[idx];
      float4 s = ((const float4*)stdv)[idx & 511];
      float4 ts;
      ts.x = t.x * s.x; ts.y = t.y * s.y; ts.z = t.z * s.z; ts.w = t.w * s.w;
      ((float4*)thrs)[idx] = ts;
    }
    if (idx < T_TOK) counts[idx] = 0;
    return;
  }

  const int bp = blockIdx.x;       // 1024 = 64 half-steps x 16 col-chunks
  const int hs = bp >> 4, cc = bp & 15;
  const int step = hs >> 1, kh = hs & 1;
  const int r0 = hs * 32;
  {
    const int sr = tid >> 7, sf = tid & 127;
    #pragma unroll 4
    for (int p = 0; p < 16; ++p) {
      const int row = p * 2 + sr;
      float4 v = *(const float4*)(w + (size_t)(r0 + row) * O_DIM + cc * 512 + sf * 4);
      *(float4*)&ls[row][sf * 4] = v;
    }
  }
  __syncthreads();

  float mus[32];
  #pragma unroll
  for (int r = 0; r < 32; ++r) mus[r] = mu[r0 + r];

  #pragma unroll
  for (int ci = 0; ci < 2; ++ci) {
    const int c = tid + ci * 256;
    const int C = cc * 512 + c;
    const int n = C >> 7, o = C & 127;
    char* tb = wt + (size_t)(n * NSTEP + step) * TILE_B + (kh * 8 + (o >> 4)) * 1024;
    float pm = 0.0f;
    #pragma unroll
    for (int g = 0; g < 4; ++g) {
      unsigned hv[4];
      unsigned hprev = 0;
      #pragma unroll
      for (int e = 0; e < 8; ++e) {
        float v = ls[g * 8 + e][c];
        pm += mus[g * 8 + e] * v;
        unsigned u = __builtin_bit_cast(unsigned, v);
        unsigned r = u + 0x7fffu + ((u >> 16) & 1u);   // RNE to bf16
        unsigned short h = (unsigned short)(r >> 16);
        if ((e & 1) == 0) hprev = h;
        else hv[e >> 1] = hprev | (((unsigned)h) << 16);
      }
      *(i32x4*)(tb + ((o & 15) + g * 16) * 16) = *(i32x4*)hv;
    }
    pm_part[(size_t)(step * 2 + kh) * O_DIM + C] = pm;
  }
}

// k1: pmb[o] = bias[o] + sum_s pm_part[s][o] (fixed order, deterministic)
__global__ void cwic_pmb(const float* __restrict__ pm_part,
                         const float* __restrict__ bias, float* __restrict__ pmb) {
  int o = blockIdx.x * 256 + threadIdx.x;
  float s = bias[o];
  #pragma unroll 8
  for (int j = 0; j < 64; ++j) s += pm_part[(size_t)j * O_DIM + o];
  pmb[o] = s;
}

// k2: masked GEMM "B-direct, 1-product, 8-wave, A-build-ahead" (R26-verified
// best: 61.8us total). With setprio (R26 > R28-without, within noise).
__global__ __launch_bounds__(512, 4) void cwic_gemm22(
    const float* __restrict__ xc, const char* __restrict__ wt,
    const float* __restrict__ thrs, const float* __restrict__ pmb,
    float* __restrict__ y, int* __restrict__ counts) {
  extern __shared__ char smem[];
  const int b = blockIdx.x;
  // XCD swizzle: the 8 token-tiles of one stripe share an XCD -> tiles L2-hot.
  const int nid = (b & 7) * 64 + (b >> 3);
  const int n = nid >> 3, tt = nid & 7;
  const int trow0 = tt * 64, ocol0 = n * 128;
  const int tid = threadIdx.x;
  const int lane = tid & 63, wid = tid >> 6;      // 8 waves
  const int wr = wid >> 2, wc = wid & 3;          // 2 x 4
  const int l15 = lane & 15, l4 = lane >> 4;
  const int t_loc = tid >> 3, kq = tid & 7;       // A staging: row (0..63), k-octet

  float* thr_s = (float*)(smem + THR_S);
  ((float4*)thr_s)[tid] = ((const float4*)(thrs + (size_t)n * I_DIM))[tid];

  const float* xrow = xc + (size_t)(trow0 + t_loc) * I_DIM + kq * 8;
  const char* wfrag = wt + (size_t)(n * NSTEP) * TILE_B + (wc * 2) * 1024 + lane * 16;

  f32x4 acc[2][2];
  #pragma unroll
  for (int mi = 0; mi < 2; ++mi)
    #pragma unroll
    for (int ni = 0; ni < 2; ++ni) acc[mi][ni] = (f32x4)(0.0f);
  int cnt = 0;

  bf16x8 bA0, bA1, bA2, bA3, bB0, bB1, bB2, bB3;
  bA0 = *(const bf16x8*)(wfrag + 0 * 1024);
  bA1 = *(const bf16x8*)(wfrag + 1 * 1024);
  bA2 = *(const bf16x8*)(wfrag + 8 * 1024);
  bA3 = *(const bf16x8*)(wfrag + 9 * 1024);
  float4 xp0 = *(const float4*)(xrow);
  float4 xp1 = *(const float4*)(xrow + 4);
  __syncthreads();  // thr_s ready

  // A-build(0) -> buf0
  {
    float4 tv0 = *(const float4*)(thr_s + kq * 8);
    float4 tv1 = *(const float4*)(thr_s + kq * 8 + 4);
    const float xs[8] = {xp0.x, xp0.y, xp0.z, xp0.w, xp1.x, xp1.y, xp1.z, xp1.w};
    const float ts[8] = {tv0.x, tv0.y, tv0.z, tv0.w, tv1.x, tv1.y, tv1.z, tv1.w};
    bf16x8 hv8;
    #pragma unroll
    for (int e = 0; e < 8; ++e) {
      bool keep = fabsf(xs[e]) > ts[e];
      cnt += keep ? 1 : 0;
      float a = keep ? xs[e] : 0.0f;
      __hip_bfloat16 h = __float2bfloat16(a);
      hv8[e] = __builtin_bit_cast(short, h);
    }
    const int ad = t_loc * 128 + ((kq * 16) ^ ((t_loc & 7) << 4));
    *(bf16x8*)(smem + 0 + ad) = hv8;
  }
  __syncthreads();  // A(0) visible

#define STEP22(STEP_I, CUR, B0, B1, B2, B3, NB0, NB1, NB2, NB3)                \
  {                                                                            \
    const int step_ = (STEP_I);                                                \
    const int s1_ = step_ + 1;                                                 \
    const int sc_ = (s1_ < NSTEP) ? s1_ : step_;                               \
    /* (1) issue B(step+1) -> other static regs */                             \
    {                                                                          \
      const char* bp_ = wfrag + (size_t)sc_ * TILE_B;                          \
      NB0 = *(const bf16x8*)(bp_ + 0 * 1024);                                  \
      NB1 = *(const bf16x8*)(bp_ + 1 * 1024);                                  \
      NB2 = *(const bf16x8*)(bp_ + 8 * 1024);                                  \
      NB3 = *(const bf16x8*)(bp_ + 9 * 1024);                                  \
    }                                                                          \
    /* (2) issue x(step+1) (latency hides under MFMA) */                       \
    float4 xn0 = *(const float4*)(xrow + sc_ * BK);                            \
    float4 xn1 = *(const float4*)(xrow + sc_ * BK + 4);                        \
    /* (3) MFMA(step): A from LDS[CUR], B from regs (landed last step) */      \
    __builtin_amdgcn_s_setprio(1);                                             \
    _Pragma("unroll") for (int s32 = 0; s32 < 2; ++s32) {                      \
      bf16x8 afh[2];                                                           \
      _Pragma("unroll") for (int mi = 0; mi < 2; ++mi) {                       \
        const int r = wr * 32 + mi * 16 + l15;                                 \
        const int ada = r * 128 + (((s32 * 64) + l4 * 16) ^ ((r & 7) << 4));   \
        afh[mi] = *(const bf16x8*)(smem + (CUR) + ada);                        \
      }                                                                        \
      bf16x8 bh0 = (s32 == 0) ? B0 : B2;                                       \
      bf16x8 bh1 = (s32 == 0) ? B1 : B3;                                       \
      _Pragma("unroll") for (int mi = 0; mi < 2; ++mi) {                       \
        acc[mi][0] = __builtin_amdgcn_mfma_f32_16x16x32_bf16(afh[mi], bh0, acc[mi][0], 0, 0, 0); \
        acc[mi][1] = __builtin_amdgcn_mfma_f32_16x16x32_bf16(afh[mi], bh1, acc[mi][1], 0, 0, 0); \
      }                                                                        \
    }                                                                          \
    __builtin_amdgcn_s_setprio(0);                                             \
    /* (4) A-build(step+1) into LDS[CUR^1] (skipped on final step) */          \
    if (s1_ < NSTEP) {                                                         \
      float4 tv0 = *(const float4*)(thr_s + s1_ * BK + kq * 8);                \
      float4 tv1 = *(const float4*)(thr_s + s1_ * BK + kq * 8 + 4);            \
      const float xs[8] = {xn0.x, xn0.y, xn0.z, xn0.w, xn1.x, xn1.y, xn1.z, xn1.w}; \
      const float ts[8] = {tv0.x, tv0.y, tv0.z, tv0.w, tv1.x, tv1.y, tv1.z, tv1.w}; \
      bf16x8 hv8;                                                              \
      _Pragma("unroll") for (int e = 0; e < 8; ++e) {                          \
        bool keep = fabsf(xs[e]) > ts[e];                                      \
        cnt += keep ? 1 : 0;                                                   \
        float a = keep ? xs[e] : 0.0f;                                         \
        __hip_bfloat16 h = __float2bfloat16(a);                                \
        hv8[e] = __builtin_bit_cast(short, h);                                 \
      }                                                                        \
      const int ad = t_loc * 128 + ((kq * 16) ^ ((t_loc & 7) << 4));           \
      *(bf16x8*)(smem + ((CUR) ^ 8192) + ad) = hv8;                            \
    }                                                                          \
    __syncthreads(); /* publish A(step+1); separates buf reuse across iters */ \
  }

  for (int sp = 0; sp < NSTEP; sp += 2) {
    STEP22(sp,     0,    bA0, bA1, bA2, bA3, bB0, bB1, bB2, bB3);
    STEP22(sp + 1, 8192, bB0, bB1, bB2, bB3, bA0, bA1, bA2, bA3);
  }
#undef STEP22

  // ---- mask-count reduce: 8 threads (kq) share one token row ----
  cnt += __shfl_xor(cnt, 1);
  cnt += __shfl_xor(cnt, 2);
  cnt += __shfl_xor(cnt, 4);
  if (kq == 0) atomicAdd(&counts[trow0 + t_loc], cnt);

  // ---- epilogue: y = acc + (post_mu + bias); C/D layout m89-verified ----
  #pragma unroll
  for (int ni = 0; ni < 2; ++ni) {
    const int o = ocol0 + wc * 32 + ni * 16 + l15;
    const float pv = pmb[o];
    #pragma unroll
    for (int mi = 0; mi < 2; ++mi) {
      const int row0 = trow0 + wr * 32 + mi * 16 + l4 * 4;
      #pragma unroll
      for (int r = 0; r < 4; ++r) {
        y[(size_t)(row0 + r) * O_DIM + o] = acc[mi][ni][r] + pv;
      }
    }
  }
}

// k3: flops outputs. flops_sparse = 16777216 * cnt/(64*2048) = 128*cnt (exact).
__global__ void cwic_fin(const int* __restrict__ counts, float* __restrict__ outF) {
  int t = blockIdx.x * 256 + threadIdx.x;
  outF[t] = 16777216.0f;
  outF[T_TOK + t] = 128.0f * (float)counts[t];
}

extern "C" void kernel_launch(void* const* d_in, const int* in_sizes, int n_in,
                              void* d_out, int out_size, void* d_ws, size_t ws_size,
                              hipStream_t stream) {
  const float* x = (const float*)d_in[0];
  const float* w = (const float*)d_in[1];
  const float* bias = (const float*)d_in[2];
  const float* thresholds = (const float*)d_in[3];
  const float* mu = (const float*)d_in[4];
  const float* stdv = (const float*)d_in[5];
  float* y = (float*)d_out;

  char* ws = (char*)d_ws;
  char* wt = ws + WT_OFF;
  float* xc = (float*)(ws + XC_OFF);
  float* thrs = (float*)(ws + THR_OFF);
  float* pm_part = (float*)(ws + PM_OFF);
  float* pmb = (float*)(ws + PMB_OFF);
  int* counts = (int*)(ws + CNT_OFF);

  cwic_prep_all<<<2048, 256, 0, stream>>>(w, mu, x, thresholds, stdv, wt,
                                          pm_part, xc, thrs, counts);
  cwic_pmb<<<32, 256, 0, stream>>>(pm_part, bias, pmb);
  cwic_gemm22<<<512, 512, SMEM22, stream>>>(xc, wt, thrs, pmb, y, counts);
  cwic_fin<<<2, 256, 0, stream>>>(counts, y + (size_t)T_TOK * O_DIM);
}